// Round 10
// baseline (528.189 us; speedup 1.0000x reference)
//
#include <hip/hip_runtime.h>
#include <hip/hip_bf16.h>

#define HID   51
#define MR    208          // 204 gate rows + y row (204) padded to 13 tiles of 16
#define SEQT  999
#define CH    111          // 999 = 9 * 111
#define NCH   9
#define EPB   16           // batch elements per block -> 256 blocks, full-width lanes
#define XST   17           // x/y LDS stride (EPB+1)
#define NTH   512          // 8 waves: w0-4 = 2 tiles, w5/w6 = 1 tile, w7 = tile12+y+xsvc
#define BSTR  72           // bcol row stride in halves (144 B: 16B-aligned, free 2-way)

typedef __attribute__((ext_vector_type(8))) short  short8;   // 8 bf16 = 4 VGPRs
typedef __attribute__((ext_vector_type(4))) float  floatx4;

// A_ext[208][64] bf16, row r = 4u+gate, PRE-SCALED by -log2(e) (i,f,o) or
// -2*log2(e) (g) so the MFMA output is directly an exp2 argument.
//   rows 0..203: cols 0..50 <- W_hh[gate*51+u][k], col 51 <- W_ih[gate*51+u]
//   row  204   : cols 0..50 <- W_fc[k] UNSCALED  (y_{t-1} falls out of the MFMA)
__global__ void prep_kernel(const float* __restrict__ W_hh,
                            const float* __restrict__ W_ih,
                            const float* __restrict__ W_fc,
                            __hip_bfloat16* __restrict__ A_ext)
{
    const float K1 = 1.442695040889f;
    int idx = blockIdx.x * blockDim.x + threadIdx.x;
    if (idx >= MR * 64) return;
    int r = idx >> 6, k = idx & 63;
    int u = r >> 2, gate = r & 3;
    float v = 0.f;
    if (r == 204) {
        if (k < HID) v = W_fc[k];
    } else if (u < HID) {
        float s = (gate == 2) ? (-2.f * K1) : (-K1);
        if (k < HID)      v = s * W_hh[(gate * HID + u) * HID + k];
        else if (k == 51) v = s * W_ih[gate * HID + u];
    }
    A_ext[idx] = __float2bfloat16(v);
}

__launch_bounds__(NTH)
__global__ void lstm_mfma_kernel(const float* __restrict__ x,
                                 const float* __restrict__ b_ih,
                                 const float* __restrict__ b_hh,
                                 const float* __restrict__ b_fc,
                                 const __hip_bfloat16* __restrict__ A_ext,
                                 float* __restrict__ out)
{
    __shared__ __hip_bfloat16 bcol[2][16 * BSTR];
    __shared__ float x_lds[(CH + 1) * XST];   // +1 lookahead for row-51 prewrite
    __shared__ float y_lds[CH * XST];         // slot tt holds y[t0 + tt - 1]

    const int tid  = threadIdx.x;
    const int w    = tid >> 6;    // wave id 0..7 (round-robin to SIMDs -> 2/SIMD)
    const int lane = tid & 63;
    const int e    = lane & 15;   // MFMA col — all 16 live
    const int g4   = lane >> 4;   // lane group
    const int e0   = blockIdx.x * EPB;

    // tile assignment: w0-4 -> tiles (2w, 2w+1); w5 -> 10; w6 -> 11; w7 -> 12
    const int  nt = (w < 5) ? 2 : 1;
    const int  T0 = (w < 5) ? 2 * w : (w + 5);
    const bool w7 = (w == 7);
    const bool yln = w7 && (g4 == 3);          // y-row (204) owner lanes
    const bool xsv = w7 && (g4 == 0);          // x-service lanes

    const float K1  = 1.442695040889f;
    const float K2N = -2.885390081777f;        // -2*log2(e)

    short8  A0[2], A1[2];
    floatx4 bq[2];
    float   cs[2];
    int     uu[2], wrow[2];

#pragma unroll
    for (int i = 0; i < 2; ++i) {
        A0[i] = short8{0,0,0,0,0,0,0,0}; A1[i] = A0[i];
        bq[i] = floatx4{0.f,0.f,0.f,0.f}; cs[i] = 0.f; uu[i] = 63; wrow[i] = 63;
    }
#pragma unroll
    for (int i = 0; i < 2; ++i) {
        if (i < nt) {
            int T = T0 + i;
            int m = T * 16 + e;
            int u = 4 * T + g4;
            A0[i] = *(const short8*)&A_ext[m * 64 + g4 * 8];
            A1[i] = *(const short8*)&A_ext[m * 64 + 32 + g4 * 8];
            uu[i] = u;
            wrow[i] = (u < HID) ? u : 63;      // u==51 lanes dump into dead row 63
            if (u < HID) {
#pragma unroll
                for (int gg = 0; gg < 4; ++gg) {
                    float s = (gg == 2) ? (-2.f * K1) : (-K1);
                    bq[i][gg] = s * (b_ih[gg * HID + u] + b_hh[gg * HID + u]);
                }
            }
        }
    }

    for (int i = tid; i < 16 * BSTR; i += NTH) {
        bcol[0][i] = __float2bfloat16(0.f);
        bcol[1][i] = __float2bfloat16(0.f);
    }
    __syncthreads();   // zero-init fully ordered before x0 seed
    if (tid < EPB)
        bcol[0][tid * BSTR + 51] = __float2bfloat16(x[(size_t)(e0 + tid) * SEQT]);
    const float bfc = b_fc[0];

    __syncthreads();

    for (int tc = 0; tc < NCH; ++tc) {
        const int t0 = tc * CH;
        for (int i2 = tid; i2 < (CH + 1) * EPB; i2 += NTH) {
            int ee = i2 / (CH + 1), tt = i2 % (CH + 1);
            int t = t0 + tt;
            x_lds[tt * XST + ee] = (t < SEQT) ? x[(size_t)(e0 + ee) * SEQT + t] : 0.f;
        }
        __syncthreads();

        for (int tt = 0; tt < CH; ++tt) {
            const int t  = t0 + tt;
            const int rp = t & 1, wp = rp ^ 1;

            short8 B0 = *(const short8*)&bcol[rp][e * BSTR + g4 * 8];
            short8 B1 = *(const short8*)&bcol[rp][e * BSTR + 32 + g4 * 8];
            const floatx4 z = {0.f, 0.f, 0.f, 0.f};

            // parallel MFMA pairs: all (up to) 4 MFMAs independent, then add
            floatx4 p0 = __builtin_amdgcn_mfma_f32_16x16x32_bf16(A0[0], B0, bq[0], 0, 0, 0);
            floatx4 q0 = __builtin_amdgcn_mfma_f32_16x16x32_bf16(A1[0], B1, z,     0, 0, 0);
            floatx4 p1, q1;
            if (nt == 2) {
                p1 = __builtin_amdgcn_mfma_f32_16x16x32_bf16(A0[1], B0, bq[1], 0, 0, 0);
                q1 = __builtin_amdgcn_mfma_f32_16x16x32_bf16(A1[1], B1, z,     0, 0, 0);
            }

#pragma unroll
            for (int i = 0; i < 2; ++i) {
                if (i < nt) {
                    floatx4 acc = (i == 0) ? (p0 + q0) : (p1 + q1);

                    float Ei = __builtin_amdgcn_exp2f(acc[0]);
                    float Ef = __builtin_amdgcn_exp2f(acc[1]);
                    float Eg = __builtin_amdgcn_exp2f(acc[2]);
                    float Eo = __builtin_amdgcn_exp2f(acc[3]);
                    float sf   = __builtin_amdgcn_rcpf(1.f + Ef);
                    float Rig  = __builtin_amdgcn_rcpf(fmaf(Ei, Eg, (Ei + Eg) + 1.f));
                    float tK   = fmaf(-K2N, Eg, K2N);          // K2N*(1-Eg), parallel w/ Rig
                    cs[i] = fmaf(sf, cs[i], tK * Rig);
                    float Ec  = __builtin_amdgcn_exp2f(cs[i]);
                    float Roc = __builtin_amdgcn_rcpf(fmaf(Eo, Ec, (Eo + Ec) + 1.f));
                    float h   = (1.f - Ec) * Roc;              // sigma(o)*tanh(c)

                    bcol[wp][e * BSTR + wrow[i]] =
                        __float2bfloat16((uu[i] < HID) ? h : 0.f);
                    if (i == 0 && yln) y_lds[tt * XST + e] = acc[0] + bfc; // y[t-1]
                }
            }
            if (xsv) bcol[wp][e * BSTR + 51] =
                         __float2bfloat16(x_lds[(tt + 1) * XST + e]);

            __syncthreads();   // the ONE barrier per step
        }
        __syncthreads();

        // flush y[t0-1 .. t0+CH-2] (slot tt <-> t0+tt-1); skip t = -1
        for (int i2 = tid; i2 < CH * EPB; i2 += NTH) {
            int ee = i2 / CH, tt = i2 % CH;
            int t = t0 + tt - 1;
            if (t >= 0)
                out[(size_t)(e0 + ee) * SEQT + t] = y_lds[tt * XST + ee];
        }
        __syncthreads();
    }

    // epilogue: y[998] from one extra MFMA pass over h_998 (in bcol[1])
    if (w7) {
        short8 B0 = *(const short8*)&bcol[1][e * BSTR + g4 * 8];
        short8 B1 = *(const short8*)&bcol[1][e * BSTR + 32 + g4 * 8];
        const floatx4 z = {0.f, 0.f, 0.f, 0.f};
        floatx4 p = __builtin_amdgcn_mfma_f32_16x16x32_bf16(A0[0], B0, bq[0], 0, 0, 0);
        floatx4 q = __builtin_amdgcn_mfma_f32_16x16x32_bf16(A1[0], B1, z,     0, 0, 0);
        floatx4 acc = p + q;
        if (g4 == 3)
            out[(size_t)(e0 + e) * SEQT + (SEQT - 1)] = acc[0] + bfc;
    }
}

extern "C" void kernel_launch(void* const* d_in, const int* in_sizes, int n_in,
                              void* d_out, int out_size, void* d_ws, size_t ws_size,
                              hipStream_t stream) {
    const float* x    = (const float*)d_in[0];
    const float* W_ih = (const float*)d_in[1];
    const float* W_hh = (const float*)d_in[2];
    const float* b_ih = (const float*)d_in[3];
    const float* b_hh = (const float*)d_in[4];
    const float* W_fc = (const float*)d_in[5];
    const float* b_fc = (const float*)d_in[6];
    float* out = (float*)d_out;

    __hip_bfloat16* A_ext = (__hip_bfloat16*)d_ws;   // 208*64*2 = 26.6 KB

    prep_kernel<<<(MR * 64 + 255) / 256, 256, 0, stream>>>(W_hh, W_ih, W_fc, A_ext);
    lstm_mfma_kernel<<<4096 / EPB, NTH, 0, stream>>>(x, b_ih, b_hh,
                                                     b_fc, A_ext, out);
}

// Round 11
// 505.164 us; speedup vs baseline: 1.0456x; 1.0456x over previous
//
#include <hip/hip_runtime.h>
#include <hip/hip_bf16.h>

#define HID   51
#define MR    208          // 204 gate rows + y row (204) padded to 13 tiles of 16
#define SEQT  999
#define CH    111          // 999 = 9 * 111
#define NCH   9
#define EPB   16           // batch elements per block -> 256 blocks, full-width lanes
#define XST   17           // x/y LDS stride (EPB+1)
#define NTH   448          // 7 waves, unit-balanced tile map (see below)
#define BSTR  72           // bcol row stride in halves (144 B: 16B-aligned)

typedef __attribute__((ext_vector_type(8))) short  short8;   // 8 bf16 = 4 VGPRs
typedef __attribute__((ext_vector_type(4))) float  floatx4;

// A_ext[208][64] bf16, row r = 4u+gate, PRE-SCALED by -log2(e) (i,f,o) or
// -2*log2(e) (g) so the MFMA output is directly an exp2 argument.
//   rows 0..203: cols 0..50 <- W_hh[gate*51+u][k], col 51 <- W_ih[gate*51+u]
//   row  204   : cols 0..50 <- W_fc[k] UNSCALED  (y_{t-1} falls out of the MFMA)
__global__ void prep_kernel(const float* __restrict__ W_hh,
                            const float* __restrict__ W_ih,
                            const float* __restrict__ W_fc,
                            __hip_bfloat16* __restrict__ A_ext)
{
    const float K1 = 1.442695040889f;
    int idx = blockIdx.x * blockDim.x + threadIdx.x;
    if (idx >= MR * 64) return;
    int r = idx >> 6, k = idx & 63;
    int u = r >> 2, gate = r & 3;
    float v = 0.f;
    if (r == 204) {
        if (k < HID) v = W_fc[k];
    } else if (u < HID) {
        float s = (gate == 2) ? (-2.f * K1) : (-K1);
        if (k < HID)      v = s * W_hh[(gate * HID + u) * HID + k];
        else if (k == 51) v = s * W_ih[gate * HID + u];
    }
    A_ext[idx] = __float2bfloat16(v);
}

__launch_bounds__(NTH)
__global__ void lstm_mfma_kernel(const float* __restrict__ x,
                                 const float* __restrict__ b_ih,
                                 const float* __restrict__ b_hh,
                                 const float* __restrict__ b_fc,
                                 const __hip_bfloat16* __restrict__ A_ext,
                                 float* __restrict__ out)
{
    __shared__ __hip_bfloat16 bcol[2][16 * BSTR];
    __shared__ float x_lds[(CH + 1) * XST];   // +1 lookahead for row-51 prewrite
    __shared__ float y_lds[CH * XST];         // slot tt holds y[t0 + tt - 1]

    const int tid  = threadIdx.x;
    const int w    = tid >> 6;    // wave id 0..6; SIMD = w & 3
    const int lane = tid & 63;
    const int e    = lane & 15;   // MFMA col — all 16 live
    const int g4   = lane >> 4;   // lane group
    const int e0   = blockIdx.x * EPB;

    // Unit-balanced tile map (tile 12 = 3 real units + y row, lighter):
    //   w0:{0,1} w1:{2,3} w2:{4,5} w3:{6,7,8} w4:{9} w5:{11,12} w6:{10}+xsvc
    // SIMD unit loads: S0(w0,w4)=12u  S1(w1,w5)=15u+y  S2(w2,w6)=12u+svc  S3(w3)=12u
    const int starts[7] = {0, 2, 4, 6, 9, 11, 10};
    const int cnts[7]   = {2, 2, 2, 3, 1, 2, 1};
    const int  tstart = starts[w];
    const int  tcnt   = cnts[w];
    const bool yw  = (w == 5);                 // wave holding tile 12 (y row)
    const bool yln = yw && (g4 == 3);          // y-row (204) owner lanes
    const bool xsv = (w == 6) && (g4 == 0);    // x-service lanes

    const float K1  = 1.442695040889f;
    const float K2N = -2.885390081777f;        // -2*log2(e)

    short8  A0[3], A1[3];
    floatx4 bq[3];
    float   cs[3];
    int     wrow[3];

#pragma unroll
    for (int i = 0; i < 3; ++i) {
        A0[i] = short8{0,0,0,0,0,0,0,0}; A1[i] = A0[i];
        bq[i] = floatx4{0.f,0.f,0.f,0.f}; cs[i] = 0.f; wrow[i] = 63;
    }
#pragma unroll
    for (int i = 0; i < 3; ++i) {
        if (i < tcnt) {
            int T = tstart + i;
            int m = T * 16 + e;
            int u = 4 * T + g4;
            A0[i] = *(const short8*)&A_ext[m * 64 + g4 * 8];
            A1[i] = *(const short8*)&A_ext[m * 64 + 32 + g4 * 8];
            wrow[i] = (u < HID) ? u : 63;      // u==51 lanes dump into dead row 63
            if (u < HID) {
#pragma unroll
                for (int gg = 0; gg < 4; ++gg) {
                    float s = (gg == 2) ? (-2.f * K1) : (-K1);
                    bq[i][gg] = s * (b_ih[gg * HID + u] + b_hh[gg * HID + u]);
                }
            }
        }
    }

    for (int i = tid; i < 16 * BSTR; i += NTH) {
        bcol[0][i] = __float2bfloat16(0.f);
        bcol[1][i] = __float2bfloat16(0.f);
    }
    __syncthreads();   // zero-init fully ordered before x0 seed
    if (tid < EPB)
        bcol[0][tid * BSTR + 51] = __float2bfloat16(x[(size_t)(e0 + tid) * SEQT]);
    const float bfc = b_fc[0];

    __syncthreads();

    for (int tc = 0; tc < NCH; ++tc) {
        const int t0 = tc * CH;
        for (int i2 = tid; i2 < (CH + 1) * EPB; i2 += NTH) {
            int ee = i2 / (CH + 1), tt = i2 % (CH + 1);
            int t = t0 + tt;
            x_lds[tt * XST + ee] = (t < SEQT) ? x[(size_t)(e0 + ee) * SEQT + t] : 0.f;
        }
        __syncthreads();

        for (int tt = 0; tt < CH; ++tt) {
            const int t  = t0 + tt;
            const int rp = t & 1, wp = rp ^ 1;

            short8 B0 = *(const short8*)&bcol[rp][e * BSTR + g4 * 8];
            short8 B1 = *(const short8*)&bcol[rp][e * BSTR + 32 + g4 * 8];

#pragma unroll
            for (int i = 0; i < 3; ++i) {
                if (i < tcnt) {
                    // chained MFMA accumulate (bias in C-input of the first)
                    floatx4 acc = __builtin_amdgcn_mfma_f32_16x16x32_bf16(A0[i], B0, bq[i], 0, 0, 0);
                    acc = __builtin_amdgcn_mfma_f32_16x16x32_bf16(A1[i], B1, acc, 0, 0, 0);

                    float Ei = __builtin_amdgcn_exp2f(acc[0]);
                    float Ef = __builtin_amdgcn_exp2f(acc[1]);
                    float Eg = __builtin_amdgcn_exp2f(acc[2]);
                    float Eo = __builtin_amdgcn_exp2f(acc[3]);
                    float sf   = __builtin_amdgcn_rcpf(1.f + Ef);
                    float Rig  = __builtin_amdgcn_rcpf(fmaf(Ei, Eg, (Ei + Eg) + 1.f));
                    float tK   = fmaf(-K2N, Eg, K2N);          // K2N*(1-Eg)
                    cs[i] = fmaf(sf, cs[i], tK * Rig);
                    float Ec  = __builtin_amdgcn_exp2f(cs[i]);
                    float Roc = __builtin_amdgcn_rcpf(fmaf(Eo, Ec, (Eo + Ec) + 1.f));
                    float h   = (1.f - Ec) * Roc;              // sigma(o)*tanh(c)

                    // unguarded: u==51 lanes (tile 12, g4==3) provably produce
                    // h==0 (their gate rows are zero) and land in dead row 63
                    bcol[wp][e * BSTR + wrow[i]] = __float2bfloat16(h);
                    if (i == 1 && yln) y_lds[tt * XST + e] = acc[0] + bfc; // y[t-1]
                }
            }
            if (xsv) bcol[wp][e * BSTR + 51] =
                         __float2bfloat16(x_lds[(tt + 1) * XST + e]);

            __syncthreads();   // the ONE barrier per step
        }
        __syncthreads();

        // flush y[t0-1 .. t0+CH-2] (slot tt <-> t0+tt-1); skip t = -1
        for (int i2 = tid; i2 < CH * EPB; i2 += NTH) {
            int ee = i2 / CH, tt = i2 % CH;
            int t = t0 + tt - 1;
            if (t >= 0)
                out[(size_t)(e0 + ee) * SEQT + t] = y_lds[tt * XST + ee];
        }
        __syncthreads();
    }

    // epilogue: y[998] from one extra MFMA pass over h_998 (in bcol[1]);
    // tile 12 lives on wave 5 at slot i=1
    if (yw) {
        short8 B0 = *(const short8*)&bcol[1][e * BSTR + g4 * 8];
        short8 B1 = *(const short8*)&bcol[1][e * BSTR + 32 + g4 * 8];
        floatx4 acc = __builtin_amdgcn_mfma_f32_16x16x32_bf16(A0[1], B0, bq[1], 0, 0, 0);
        acc = __builtin_amdgcn_mfma_f32_16x16x32_bf16(A1[1], B1, acc, 0, 0, 0);
        if (g4 == 3)
            out[(size_t)(e0 + e) * SEQT + (SEQT - 1)] = acc[0] + bfc;
    }
}

extern "C" void kernel_launch(void* const* d_in, const int* in_sizes, int n_in,
                              void* d_out, int out_size, void* d_ws, size_t ws_size,
                              hipStream_t stream) {
    const float* x    = (const float*)d_in[0];
    const float* W_ih = (const float*)d_in[1];
    const float* W_hh = (const float*)d_in[2];
    const float* b_ih = (const float*)d_in[3];
    const float* b_hh = (const float*)d_in[4];
    const float* W_fc = (const float*)d_in[5];
    const float* b_fc = (const float*)d_in[6];
    float* out = (float*)d_out;

    __hip_bfloat16* A_ext = (__hip_bfloat16*)d_ws;   // 208*64*2 = 26.6 KB

    prep_kernel<<<(MR * 64 + 255) / 256, 256, 0, stream>>>(W_hh, W_ih, W_fc, A_ext);
    lstm_mfma_kernel<<<4096 / EPB, NTH, 0, stream>>>(x, b_ih, b_hh,
                                                     b_fc, A_ext, out);
}

// Round 12
// 460.650 us; speedup vs baseline: 1.1466x; 1.0966x over previous
//
#include <hip/hip_runtime.h>
#include <hip/hip_bf16.h>

#define HID   51
#define MR    208          // 204 gate rows + y row (204) padded to 13 tiles of 16
#define SEQT  999
#define CH    111          // 999 = 9 * 111
#define NCH   9
#define EPB   16           // batch elements per block -> 256 blocks, full-width lanes
#define XST   17           // x/y LDS stride (EPB+1)
#define NTH   512          // 8 waves -> exactly 2 per SIMD (no solo-SIMD pacer)
#define BSTR  72           // bcol row stride in halves (144 B: 16B-aligned)

typedef __attribute__((ext_vector_type(8))) short  short8;   // 8 bf16 = 4 VGPRs
typedef __attribute__((ext_vector_type(4))) float  floatx4;

// A_ext[208][64] bf16, row r = 4u+gate, PRE-SCALED by -log2(e) (i,f,o) or
// -2*log2(e) (g) so the MFMA output is directly an exp2 argument.
//   rows 0..203: cols 0..50 <- W_hh[gate*51+u][k], col 51 <- W_ih[gate*51+u]
//   row  204   : cols 0..50 <- W_fc[k] UNSCALED  (y_{t-1} falls out of the MFMA)
__global__ void prep_kernel(const float* __restrict__ W_hh,
                            const float* __restrict__ W_ih,
                            const float* __restrict__ W_fc,
                            __hip_bfloat16* __restrict__ A_ext)
{
    const float K1 = 1.442695040889f;
    int idx = blockIdx.x * blockDim.x + threadIdx.x;
    if (idx >= MR * 64) return;
    int r = idx >> 6, k = idx & 63;
    int u = r >> 2, gate = r & 3;
    float v = 0.f;
    if (r == 204) {
        if (k < HID) v = W_fc[k];
    } else if (u < HID) {
        float s = (gate == 2) ? (-2.f * K1) : (-K1);
        if (k < HID)      v = s * W_hh[(gate * HID + u) * HID + k];
        else if (k == 51) v = s * W_ih[gate * HID + u];
    }
    A_ext[idx] = __float2bfloat16(v);
}

__launch_bounds__(NTH)
__global__ void lstm_mfma_kernel(const float* __restrict__ x,
                                 const float* __restrict__ b_ih,
                                 const float* __restrict__ b_hh,
                                 const float* __restrict__ b_fc,
                                 const __hip_bfloat16* __restrict__ A_ext,
                                 float* __restrict__ out)
{
    __shared__ __hip_bfloat16 bcol[2][16 * BSTR];
    __shared__ float x_lds[(CH + 1) * XST];   // +1 lookahead for row-51 prewrite
    __shared__ float y_lds[CH * XST];         // slot tt holds y[t0 + tt - 1]

    const int tid  = threadIdx.x;
    const int w    = tid >> 6;    // wave id 0..7; SIMD = w & 3 -> 2 waves each
    const int lane = tid & 63;
    const int e    = lane & 15;   // MFMA col — all 16 live
    const int g4   = lane >> 4;   // lane group
    const int e0   = blockIdx.x * EPB;

    // Tile map (R10 topology, R9 inner loop):
    //   w0:{0,1} w1:{2,3} w2:{4,5} w3:{6,7} w4:{8,9} w5:{10} w6:{11}+xsvc w7:{12}+y
    // SIMD tile loads: S0(w0,w4)=4  S1(w1,w5)=3  S2(w2,w6)=3+svc  S3(w3,w7)=3+y
    const int starts[8] = {0, 2, 4, 6, 8, 10, 11, 12};
    const int cnts[8]   = {2, 2, 2, 2, 2, 1, 1, 1};
    const int  tstart = starts[w];
    const int  tcnt   = cnts[w];
    const bool yw  = (w == 7);                 // wave holding tile 12 (y row)
    const bool yln = yw && (g4 == 3);          // y-row (204) owner lanes
    const bool xsv = (w == 6) && (g4 == 0);    // x-service lanes

    const float K1  = 1.442695040889f;
    const float K2N = -2.885390081777f;        // -2*log2(e)

    short8  A0[2], A1[2];
    floatx4 bq[2];
    float   cs[2];
    int     wrow[2];

#pragma unroll
    for (int i = 0; i < 2; ++i) {
        A0[i] = short8{0,0,0,0,0,0,0,0}; A1[i] = A0[i];
        bq[i] = floatx4{0.f,0.f,0.f,0.f}; cs[i] = 0.f; wrow[i] = 63;
    }
#pragma unroll
    for (int i = 0; i < 2; ++i) {
        if (i < tcnt) {
            int T = tstart + i;
            int m = T * 16 + e;
            int u = 4 * T + g4;
            A0[i] = *(const short8*)&A_ext[m * 64 + g4 * 8];
            A1[i] = *(const short8*)&A_ext[m * 64 + 32 + g4 * 8];
            wrow[i] = (u < HID) ? u : 63;      // u==51 lanes dump into dead row 63
            if (u < HID) {
#pragma unroll
                for (int gg = 0; gg < 4; ++gg) {
                    float s = (gg == 2) ? (-2.f * K1) : (-K1);
                    bq[i][gg] = s * (b_ih[gg * HID + u] + b_hh[gg * HID + u]);
                }
            }
        }
    }

    for (int i = tid; i < 16 * BSTR; i += NTH) {
        bcol[0][i] = __float2bfloat16(0.f);
        bcol[1][i] = __float2bfloat16(0.f);
    }
    __syncthreads();   // zero-init fully ordered before x0 seed
    if (tid < EPB)
        bcol[0][tid * BSTR + 51] = __float2bfloat16(x[(size_t)(e0 + tid) * SEQT]);
    const float bfc = b_fc[0];

    __syncthreads();

    for (int tc = 0; tc < NCH; ++tc) {
        const int t0 = tc * CH;
        for (int i2 = tid; i2 < (CH + 1) * EPB; i2 += NTH) {
            int ee = i2 / (CH + 1), tt = i2 % (CH + 1);
            int t = t0 + tt;
            x_lds[tt * XST + ee] = (t < SEQT) ? x[(size_t)(e0 + ee) * SEQT + t] : 0.f;
        }
        __syncthreads();

        for (int tt = 0; tt < CH; ++tt) {
            const int t  = t0 + tt;
            const int rp = t & 1, wp = rp ^ 1;

            short8 B0 = *(const short8*)&bcol[rp][e * BSTR + g4 * 8];
            short8 B1 = *(const short8*)&bcol[rp][e * BSTR + 32 + g4 * 8];

#pragma unroll
            for (int i = 0; i < 2; ++i) {
                if (i < tcnt) {
                    // chained MFMA accumulate (bias in C-input of the first)
                    floatx4 acc = __builtin_amdgcn_mfma_f32_16x16x32_bf16(A0[i], B0, bq[i], 0, 0, 0);
                    acc = __builtin_amdgcn_mfma_f32_16x16x32_bf16(A1[i], B1, acc, 0, 0, 0);

                    float Ei = __builtin_amdgcn_exp2f(acc[0]);
                    float Ef = __builtin_amdgcn_exp2f(acc[1]);
                    float Eg = __builtin_amdgcn_exp2f(acc[2]);
                    float Eo = __builtin_amdgcn_exp2f(acc[3]);
                    float sf   = __builtin_amdgcn_rcpf(1.f + Ef);
                    float Rig  = __builtin_amdgcn_rcpf(fmaf(Ei, Eg, (Ei + Eg) + 1.f));
                    float tK   = fmaf(-K2N, Eg, K2N);          // K2N*(1-Eg)
                    cs[i] = fmaf(sf, cs[i], tK * Rig);
                    float Ec  = __builtin_amdgcn_exp2f(cs[i]);
                    float Roc = __builtin_amdgcn_rcpf(fmaf(Eo, Ec, (Eo + Ec) + 1.f));
                    float h   = (1.f - Ec) * Roc;              // sigma(o)*tanh(c)

                    // unguarded: tile-12 g4==3 lanes provably produce h==0
                    // (their gate rows are zero) and land in dead row 63
                    bcol[wp][e * BSTR + wrow[i]] = __float2bfloat16(h);
                    if (i == 0 && yln) y_lds[tt * XST + e] = acc[0] + bfc; // y[t-1]
                }
            }
            if (xsv) bcol[wp][e * BSTR + 51] =
                         __float2bfloat16(x_lds[(tt + 1) * XST + e]);

            __syncthreads();   // the ONE barrier per step
        }
        __syncthreads();

        // flush y[t0-1 .. t0+CH-2] (slot tt <-> t0+tt-1); skip t = -1
        for (int i2 = tid; i2 < CH * EPB; i2 += NTH) {
            int ee = i2 / CH, tt = i2 % CH;
            int t = t0 + tt - 1;
            if (t >= 0)
                out[(size_t)(e0 + ee) * SEQT + t] = y_lds[tt * XST + ee];
        }
        __syncthreads();
    }

    // epilogue: y[998] from one extra MFMA pass over h_998 (in bcol[1]);
    // tile 12 lives on wave 7 at slot i=0
    if (yw) {
        short8 B0 = *(const short8*)&bcol[1][e * BSTR + g4 * 8];
        short8 B1 = *(const short8*)&bcol[1][e * BSTR + 32 + g4 * 8];
        floatx4 acc = __builtin_amdgcn_mfma_f32_16x16x32_bf16(A0[0], B0, bq[0], 0, 0, 0);
        acc = __builtin_amdgcn_mfma_f32_16x16x32_bf16(A1[0], B1, acc, 0, 0, 0);
        if (g4 == 3)
            out[(size_t)(e0 + e) * SEQT + (SEQT - 1)] = acc[0] + bfc;
    }
}

extern "C" void kernel_launch(void* const* d_in, const int* in_sizes, int n_in,
                              void* d_out, int out_size, void* d_ws, size_t ws_size,
                              hipStream_t stream) {
    const float* x    = (const float*)d_in[0];
    const float* W_ih = (const float*)d_in[1];
    const float* W_hh = (const float*)d_in[2];
    const float* b_ih = (const float*)d_in[3];
    const float* b_hh = (const float*)d_in[4];
    const float* W_fc = (const float*)d_in[5];
    const float* b_fc = (const float*)d_in[6];
    float* out = (float*)d_out;

    __hip_bfloat16* A_ext = (__hip_bfloat16*)d_ws;   // 208*64*2 = 26.6 KB

    prep_kernel<<<(MR * 64 + 255) / 256, 256, 0, stream>>>(W_hh, W_ih, W_fc, A_ext);
    lstm_mfma_kernel<<<4096 / EPB, NTH, 0, stream>>>(x, b_ih, b_hh,
                                                     b_fc, A_ext, out);
}